// Round 6
// baseline (451.355 us; speedup 1.0000x reference)
//
#include <hip/hip_runtime.h>
#include <math.h>

#define EPSF 1e-10f
#define P_NODES (1 << 20)   // H*W per tree
#define T_F 4096            // full-walk frontier bound

// Native clang vector types — required by __builtin_nontemporal_*.
typedef float vf4 __attribute__((ext_vector_type(4)));
typedef float vf2 __attribute__((ext_vector_type(2)));

// Per-node record written by K1 (16 B, streamed, no gathers):
//   { x, score, par (bit-cast), pad }
// The chain walk obtains the parent's x from the hop read itself, so the
// x[par] random gather (4.2M reads, ~1/3 of the old random-read wall)
// disappears entirely. S(p) = S(par) + (x[p]-x[par])*score[p];
// S(root) = x*score.
//
// fin2[p] = { x[p], S(p) } (8 B) is the terminal-resolution record: a chunk
// walk ending at c < lo does ONE 8B read to get both the anchor's x and its
// final sum.

// ---------------------------------------------------------------------------
// XCD-pinned block decomposition. HW dispatches blockIdx.x round-robin over
// the 8 XCDs (blockIdx.x % 8 == XCD). With nTrees == 4, tree t owns XCDs
// {2t, 2t+1}: its random-read working set (records + fin2 prefix) stays in
// 2 private 4 MiB L2s. Perf heuristic only — mapping is bijective, so
// correctness never depends on XCD assignment. Requires gridDim.x % 8 == 0
// (all grids here are) and nTrees == 4 (fixed by harness shape B=2,N=2).
// ---------------------------------------------------------------------------
__device__ __forceinline__ void tree_decomp(int b, int& tree, int& jj)
{
    tree = (b & 7) >> 1;                 // XCD pair -> tree
    jj   = ((b >> 3) << 1) | (b & 1);    // within-tree block index
}

// ---------------------------------------------------------------------------
// K1: score = sigmoid(feats(attrs).w + b); write {x, score, par} streamed.
// attrs tile staged through LDS with float4 coalesced NT loads. No random
// reads at all.
// ---------------------------------------------------------------------------
__global__ __launch_bounds__(256) void score_kernel(
    const float* __restrict__ x,
    const float* __restrict__ weight,
    const float* __restrict__ bias,
    const float* __restrict__ attrs,
    const int*   __restrict__ parents,
    float4*      __restrict__ rec,
    int N)
{
    __shared__ float sA[256 * 15];

    const int t = threadIdx.x;
    int tree, jj;
    tree_decomp(blockIdx.x, tree, jj);
    const int blockBase = (tree << 20) + (jj << 8);
    const int idx = blockBase + t;

    // 256 rows x 15 floats = 960 float4 loads, fully coalesced, 16 B/lane.
    const vf4* ab4 = (const vf4*)(attrs + (size_t)blockBase * 15);
    vf4* sA4 = (vf4*)sA;
#pragma unroll
    for (int k = t; k < 960; k += 256)
        sA4[k] = __builtin_nontemporal_load(&ab4[k]);

    const int n    = tree % N;
    const float* w = weight + n * 17;
    const float  b = bias[n];

    __syncthreads();

    const float* a = &sA[t * 15];

    float acc = b;
    acc += a[0] * w[0];
    acc += a[1] * w[1];
    acc += a[2] * w[2];
    acc += a[3] * w[3];
    acc += a[4] * w[4];

    const float a5 = a[5];
    const float a6 = a[6];
    const float a7 = a[7];

    acc += __logf(fabsf(a6)    + EPSF) * w[5];
    acc += __logf(fabsf(a7)    + EPSF) * w[6];
    acc += __logf(fabsf(a[8])  + EPSF) * w[7];
    acc += __logf(fabsf(a[9])  + EPSF) * w[8];
    acc += __logf(fabsf(a[10]) + EPSF) * w[9];
    acc += __logf(fabsf(a[11]) + EPSF) * w[10];
    acc += __logf(fabsf(a[12]) + EPSF) * w[11];
    acc += __logf(fabsf(a[13]) + EPSF) * w[12];
    acc += __logf(fabsf(a[14]) + EPSF) * w[13];

    const float lshape = __fsqrt_rn(a7) / (__fsqrt_rn(a6) + EPSF);
    acc += lshape * w[14];
    acc += __cosf(a5) * w[15];
    acc += __sinf(a5) * w[16];

    const float score = 1.0f / (1.0f + __expf(-acc));

    const int p   = idx & (P_NODES - 1);
    const int par = parents[idx];

    float4 r;
    r.x = x[idx];
    r.y = score;
    r.z = __int_as_float(par == p ? -1 : par);   // root (p==0) -> -1
    r.w = 0.0f;
    rec[idx] = r;
}

// ---------------------------------------------------------------------------
// K2: frontier — exact walks for p < T_F. Hop region 64 KB/tree, L2/L1-hot.
// Writes out[p] (final, NT) and fin2[p] = {x[p], S(p)}.
// ---------------------------------------------------------------------------
__global__ __launch_bounds__(256) void frontier_kernel(
    const float4* __restrict__ rec,
    float2*       __restrict__ fin2,
    float*        __restrict__ out)
{
    int tree, jj;
    tree_decomp(blockIdx.x, tree, jj);
    const int p    = (jj << 8) + threadIdx.x;     // < T_F
    const int base = tree << 20;
    const float4* tp = rec + base;

    float4 r = tp[p];
    const float ox = r.x;
    float s  = 0.0f;
    float cx = r.x, csc = r.y;
    int   c  = __float_as_int(r.z);
    while (c >= 0) {
        float4 q = tp[c];
        s  += (cx - q.x) * csc;
        cx  = q.x; csc = q.y;
        c   = __float_as_int(q.z);
    }
    s += cx * csc;                                // root term

    __builtin_nontemporal_store(s, out + base + p);
    vf2 f; f.x = ox; f.y = s;
    *(vf2*)(fin2 + base + p) = f;
}

// ---------------------------------------------------------------------------
// K3..: chunk propagation for [lo, lo + blocksPerTree*2048): 8 independent
// chains per thread. Walk while cur.par >= lo (hop read supplies parent x),
// then one fin2 read resolves {x_anchor, S_anchor}. E[hops] = 0.386 for
// ratio-2 chunks -> ~1.39 random reads/node. All state scalar (rule #20).
// last!=0 -> fin2 never read again: skip the store.
// ---------------------------------------------------------------------------
#define CHAIN_STEP(K)                                                        \
    if (a##K) {                                                              \
        float4 q = tp[c##K];                                                 \
        s##K  += (cx##K - q.x) * sc##K;                                      \
        cx##K  = q.x; sc##K = q.y;                                           \
        c##K   = __float_as_int(q.z);                                        \
        a##K   = (c##K >= lo);                                               \
    }

__global__ __launch_bounds__(256) void chunk8_kernel(
    const float4* __restrict__ rec,
    float2*       __restrict__ fin2,
    float*        __restrict__ out,
    int lo, int last)
{
    int tree, jj;
    tree_decomp(blockIdx.x, tree, jj);
    const int base = tree << 20;
    const float4* tp = rec  + base;
    float2*       tf = fin2 + base;
    float*        to = out  + base;
    const int S = lo + jj * 2048 + threadIdx.x;

    // 8 nodes, stride 256 — coalesced dwordx4 self-loads.
    float4 r0 = tp[S];
    float4 r1 = tp[S +  256];
    float4 r2 = tp[S +  512];
    float4 r3 = tp[S +  768];
    float4 r4 = tp[S + 1024];
    float4 r5 = tp[S + 1280];
    float4 r6 = tp[S + 1536];
    float4 r7 = tp[S + 1792];

    float ox0 = r0.x, cx0 = r0.x, sc0 = r0.y; int c0 = __float_as_int(r0.z);
    float ox1 = r1.x, cx1 = r1.x, sc1 = r1.y; int c1 = __float_as_int(r1.z);
    float ox2 = r2.x, cx2 = r2.x, sc2 = r2.y; int c2 = __float_as_int(r2.z);
    float ox3 = r3.x, cx3 = r3.x, sc3 = r3.y; int c3 = __float_as_int(r3.z);
    float ox4 = r4.x, cx4 = r4.x, sc4 = r4.y; int c4 = __float_as_int(r4.z);
    float ox5 = r5.x, cx5 = r5.x, sc5 = r5.y; int c5 = __float_as_int(r5.z);
    float ox6 = r6.x, cx6 = r6.x, sc6 = r6.y; int c6 = __float_as_int(r6.z);
    float ox7 = r7.x, cx7 = r7.x, sc7 = r7.y; int c7 = __float_as_int(r7.z);

    float s0 = 0.f, s1 = 0.f, s2 = 0.f, s3 = 0.f;
    float s4 = 0.f, s5 = 0.f, s6 = 0.f, s7 = 0.f;

    bool a0 = (c0 >= lo), a1 = (c1 >= lo), a2 = (c2 >= lo), a3 = (c3 >= lo);
    bool a4 = (c4 >= lo), a5 = (c5 >= lo), a6 = (c6 >= lo), a7 = (c7 >= lo);

    while (a0 | a1 | a2 | a3 | a4 | a5 | a6 | a7) {
        CHAIN_STEP(0) CHAIN_STEP(1) CHAIN_STEP(2) CHAIN_STEP(3)
        CHAIN_STEP(4) CHAIN_STEP(5) CHAIN_STEP(6) CHAIN_STEP(7)
    }

    // c < lo here (p >= lo >= 4K is never the root, so c >= 0).
    // 8 independent terminal gathers, one 8B line-touch each.
    float2 f0 = tf[c0], f1 = tf[c1], f2 = tf[c2], f3 = tf[c3];
    float2 f4 = tf[c4], f5 = tf[c5], f6 = tf[c6], f7 = tf[c7];
    s0 += (cx0 - f0.x) * sc0 + f0.y;
    s1 += (cx1 - f1.x) * sc1 + f1.y;
    s2 += (cx2 - f2.x) * sc2 + f2.y;
    s3 += (cx3 - f3.x) * sc3 + f3.y;
    s4 += (cx4 - f4.x) * sc4 + f4.y;
    s5 += (cx5 - f5.x) * sc5 + f5.y;
    s6 += (cx6 - f6.x) * sc6 + f6.y;
    s7 += (cx7 - f7.x) * sc7 + f7.y;

    // out is never re-read: NT, keep L2 for records/fin2.
    __builtin_nontemporal_store(s0, to + S);
    __builtin_nontemporal_store(s1, to + S +  256);
    __builtin_nontemporal_store(s2, to + S +  512);
    __builtin_nontemporal_store(s3, to + S +  768);
    __builtin_nontemporal_store(s4, to + S + 1024);
    __builtin_nontemporal_store(s5, to + S + 1280);
    __builtin_nontemporal_store(s6, to + S + 1536);
    __builtin_nontemporal_store(s7, to + S + 1792);

    if (!last) {
        vf2 g0; g0.x = ox0; g0.y = s0; *(vf2*)(tf + S)        = g0;
        vf2 g1; g1.x = ox1; g1.y = s1; *(vf2*)(tf + S +  256) = g1;
        vf2 g2; g2.x = ox2; g2.y = s2; *(vf2*)(tf + S +  512) = g2;
        vf2 g3; g3.x = ox3; g3.y = s3; *(vf2*)(tf + S +  768) = g3;
        vf2 g4; g4.x = ox4; g4.y = s4; *(vf2*)(tf + S + 1024) = g4;
        vf2 g5; g5.x = ox5; g5.y = s5; *(vf2*)(tf + S + 1280) = g5;
        vf2 g6; g6.x = ox6; g6.y = s6; *(vf2*)(tf + S + 1536) = g6;
        vf2 g7; g7.x = ox7; g7.y = s7; *(vf2*)(tf + S + 1792) = g7;
    }
}

extern "C" void kernel_launch(void* const* d_in, const int* in_sizes, int n_in,
                              void* d_out, int out_size, void* d_ws, size_t ws_size,
                              hipStream_t stream)
{
    const float* x       = (const float*)d_in[0];
    const float* weight  = (const float*)d_in[1];
    const float* bias    = (const float*)d_in[2];
    const float* attrs   = (const float*)d_in[3];
    const int*   parents = (const int*)d_in[4];
    float*       out     = (float*)d_out;

    const int total  = in_sizes[0];           // B*N*P = 4194304
    const int N      = in_sizes[1] / 17;      // weight is (N,17,1)
    const int nTrees = total >> 20;           // 4

    float4* rec  = (float4*)d_ws;                         // 64 MB
    float2* fin2 = (float2*)((char*)d_ws + ((size_t)total * 16)); // +32 MB

    const int block = 256;

    // K1: streaming score + record pack. 16384 blocks (mult of 8, pinned).
    score_kernel<<<total / block, block, 0, stream>>>(x, weight, bias, attrs,
                                                      parents, rec, N);

    // K2: full walks [0, 4K). 16 blocks/tree -> 64.
    frontier_kernel<<<(T_F / block) * nTrees, block, 0, stream>>>(rec, fin2, out);

    // K3..K10: ratio-2 ladder 4K -> 1M. blocks/tree = span/2048.
    for (int lo = T_F; lo < P_NODES; lo <<= 1) {
        const int span = lo;                  // [lo, 2*lo)
        const int last = (lo << 1) >= P_NODES;
        chunk8_kernel<<<(span / 2048) * nTrees, block, 0, stream>>>(
            rec, fin2, out, lo, last);
    }
}